// Round 6
// baseline (13123.219 us; speedup 1.0000x reference)
//
#include <hip/hip_runtime.h>
#include <hip/hip_bf16.h>

typedef unsigned short u16;
typedef unsigned int u32;
typedef unsigned long long u64;
typedef __attribute__((ext_vector_type(8))) short short8v;      // MFMA bf16 frag (4 VGPR)
typedef __attribute__((ext_vector_type(8))) unsigned short ushort8v;
typedef __attribute__((ext_vector_type(4))) float float4v;
typedef __attribute__((ext_vector_type(4))) unsigned int uint4v;

#define S_LEN 1024
#define BATCH 256
#define VOCAB 32000
#define EMBED 512
#define HIDDEN 1024

__device__ inline u16 f2bf(float f) {
  return __builtin_bit_cast(u16, __float2bfloat16(f));  // RNE
}

// Coherent (sc0|sc1 = cpol 17: L2-bypass, L3 coherent point) pipelined
// 16B buffer load/store. Plain VMEM ops -> compiler-scheduled/pipelined.
__device__ inline short8v cohload16(const u16* base, int voff) {
  __amdgpu_buffer_rsrc_t r =
      __builtin_amdgcn_make_buffer_rsrc((void*)base, (short)0, -1, 0x00020000);
  uint4v d = __builtin_amdgcn_raw_buffer_load_b128(r, voff, 0, 17);
  return __builtin_bit_cast(short8v, d);
}
__device__ inline void cohstore16(u16* base, int voff, ushort8v v) {
  __amdgpu_buffer_rsrc_t r =
      __builtin_amdgcn_make_buffer_rsrc((void*)base, (short)0, -1, 0x00020000);
  __builtin_amdgcn_raw_buffer_store_b128(__builtin_bit_cast(uint4v, v), r, voff, 0, 17);
}

// ---------------- prep: W_ih -> bf16, zero hbuf + flags ----------------
__global__ __launch_bounds__(256) void prep_kernel(const float* __restrict__ wih,
                                                   u16* __restrict__ wih16,
                                                   u16* __restrict__ hbuf,
                                                   u32* __restrict__ flag) {
  int i = blockIdx.x * 256 + threadIdx.x;
  const int NW = (HIDDEN * EMBED) / 8;      // 65536
  const int NH = (2 * BATCH * HIDDEN) / 8;  // 65536
  if (i < NW) {
    const float* s = wih + (size_t)i * 8;
    float4v a = *(const float4v*)s;
    float4v b = *(const float4v*)(s + 4);
    ushort8v v;
    v[0]=f2bf(a[0]); v[1]=f2bf(a[1]); v[2]=f2bf(a[2]); v[3]=f2bf(a[3]);
    v[4]=f2bf(b[0]); v[5]=f2bf(b[1]); v[6]=f2bf(b[2]); v[7]=f2bf(b[3]);
    *(ushort8v*)(wih16 + (size_t)i * 8) = v;
  } else if (i < NW + NH) {
    int j = i - NW;
    ushort8v z = {0,0,0,0,0,0,0,0};
    *(ushort8v*)(hbuf + (size_t)j * 8) = z;
  } else if (i < NW + NH + 64) {
    flag[i - NW - NH] = 0u;
  }
}

// ---------------- embed + input projection GEMM ----------------
__global__ __launch_bounds__(256) void gemm_embed(const int* __restrict__ xseq,
                                                  const float* __restrict__ emb,
                                                  const u16* __restrict__ wih16,
                                                  const float* __restrict__ bih,
                                                  float* __restrict__ out) {
  __shared__ u16 At[128 * 64];   // swizzled: chunk ^= (row&7)
  __shared__ u16 Bt[128 * 64];
  __shared__ int idxc[128];
  const int tid = threadIdx.x;
  const int bid = blockIdx.x;
  const int mt = bid >> 3;       // 2048 m-tiles
  const int nt = bid & 7;        // 8 n-tiles
  if (tid < 128) idxc[tid] = xseq[mt * 128 + tid];
  const int lane = tid & 63;
  const int wid = tid >> 6;
  const int wr = wid >> 1, wc = wid & 1;
  float4v acc[4][4] = {};
  __syncthreads();
  for (int kk = 0; kk < EMBED; kk += 64) {
    #pragma unroll
    for (int s = 0; s < 4; s++) {
      int it = tid + s * 256;          // 1024 items = 128 rows x 8 chunks(16B)
      int row = it >> 3, c = it & 7;
      const float* sa = emb + (size_t)idxc[row] * EMBED + kk + c * 8;
      float4v a0 = *(const float4v*)sa;
      float4v a1 = *(const float4v*)(sa + 4);
      ushort8v va;
      va[0]=f2bf(a0[0]); va[1]=f2bf(a0[1]); va[2]=f2bf(a0[2]); va[3]=f2bf(a0[3]);
      va[4]=f2bf(a1[0]); va[5]=f2bf(a1[1]); va[6]=f2bf(a1[2]); va[7]=f2bf(a1[3]);
      *(ushort8v*)(At + row * 64 + ((c ^ (row & 7)) * 8)) = va;
      ushort8v vb = *(const ushort8v*)(wih16 + (size_t)(nt * 128 + row) * EMBED + kk + c * 8);
      *(ushort8v*)(Bt + row * 64 + ((c ^ (row & 7)) * 8)) = vb;
    }
    __syncthreads();
    #pragma unroll
    for (int ks = 0; ks < 2; ks++) {
      short8v af[4], bf[4];
      #pragma unroll
      for (int i = 0; i < 4; i++) {
        int r = wr * 64 + i * 16 + (lane & 15);
        int ca = (ks * 4 + (lane >> 4)) ^ (r & 7);
        af[i] = *(const short8v*)(At + r * 64 + ca * 8);
        int cc = wc * 64 + i * 16 + (lane & 15);
        int cb = (ks * 4 + (lane >> 4)) ^ (cc & 7);
        bf[i] = *(const short8v*)(Bt + cc * 64 + cb * 8);
      }
      #pragma unroll
      for (int i = 0; i < 4; i++)
        #pragma unroll
        for (int j = 0; j < 4; j++)
          acc[i][j] = __builtin_amdgcn_mfma_f32_16x16x32_bf16(af[i], bf[j], acc[i][j], 0, 0, 0);
    }
    __syncthreads();
  }
  #pragma unroll
  for (int j = 0; j < 4; j++) {
    int cg = nt * 128 + wc * 64 + j * 16 + (lane & 15);
    float bias = bih[cg];
    #pragma unroll
    for (int i = 0; i < 4; i++) {
      int rg = mt * 128 + wr * 64 + i * 16 + (lane >> 4) * 4;
      #pragma unroll
      for (int q = 0; q < 4; q++)
        out[(size_t)(rg + q) * HIDDEN + cg] = acc[i][j][q] + bias;
    }
  }
}

// ---------------- recurrence ----------------
// 64 blocks = 4 groups (64 batch rows) x 16 j-tiles (64 hidden cols).
// W_hh tile resident in LDS. Cross-block h exchange via sc0|sc1 buffer
// loads/stores (L2-bypass, coherent at L3, compiler-pipelined). Flags are
// agent-scope relaxed atomics. No fences, no cache invalidates.
__global__ __launch_bounds__(256) void rnn_rec(const float* __restrict__ whh,
                                               const float* __restrict__ bhh,
                                               u16* __restrict__ hbuf,
                                               float* __restrict__ out,
                                               u32* __restrict__ flag) {
  extern __shared__ u16 smem[];
  u16* Wt = smem;                    // [64][1024] bf16, chunk ^= (row&7)
  u16* hstage = smem + 64 * 1024;    // [64][64] bf16 staging for coop store
  const int tid = threadIdx.x;
  const int lane = tid & 63, w = tid >> 6;   // 4 waves, wave tile 16 rows x 64 cols
  const int g = blockIdx.x & 3;
  const int jt = blockIdx.x >> 2;
  // prologue: load + convert + swizzle W_hh rows [jt*64, jt*64+64)
  for (int i = tid; i < 64 * 128; i += 256) {
    int row = i >> 7, c = i & 127;   // c = 16B chunk (8 elems)
    const float* s = whh + (size_t)(jt * 64 + row) * HIDDEN + c * 8;
    float4v a = *(const float4v*)s;
    float4v b = *(const float4v*)(s + 4);
    ushort8v v;
    v[0]=f2bf(a[0]); v[1]=f2bf(a[1]); v[2]=f2bf(a[2]); v[3]=f2bf(a[3]);
    v[4]=f2bf(b[0]); v[5]=f2bf(b[1]); v[6]=f2bf(b[2]); v[7]=f2bf(b[3]);
    *(ushort8v*)(Wt + row * 1024 + ((c ^ (row & 7)) * 8)) = v;
  }
  const int l15 = lane & 15, l4 = lane >> 4;
  float bh[4];
  #pragma unroll
  for (int jj = 0; jj < 4; jj++) bh[jj] = bhh[jt * 64 + jj * 16 + l15];
  __syncthreads();

  const int rA  = g * 64 + w * 16 + l15;      // A-frag row (global batch row)
  const int rO0 = g * 64 + w * 16 + l4 * 4;   // C rows (+q)
  const int cO0 = jt * 64 + l15;              // C cols (+jj*16)
  const int lr0 = w * 16 + l4 * 4;            // local C row in hstage
  // cooperative hbuf store mapping: thread -> 32B chunk of the 8KB tile
  const int sr = tid >> 2;                    // staging row 0..63
  const int sc = (tid & 3) * 16;              // staging col (u16 units)
  const int aoff0 = rA * (HIDDEN * 2) + l4 * 16;                 // byte offset in slot
  const int soff0 = (g * 64 + sr) * (HIDDEN * 2) + (jt * 64 + sc) * 2;

  for (int t = 0; t < S_LEN; t++) {
    const int p = t & 1;
    float* outt = out + (size_t)t * (BATCH * HIDDEN);
    // xp prefetch (in flight during the poll)
    float xp[4][4];
    #pragma unroll
    for (int jj = 0; jj < 4; jj++)
      #pragma unroll
      for (int q = 0; q < 4; q++)
        xp[jj][q] = outt[(size_t)(rO0 + q) * HIDDEN + cO0 + jj * 16];
    // wait for the 16 producers of h_{t-1} in this group (parallel poll)
    if (t > 0) {
      if (tid < 16) {
        u32* f = flag + g * 16 + tid;
        while (__hip_atomic_load(f, __ATOMIC_RELAXED, __HIP_MEMORY_SCOPE_AGENT) < (u32)t) { }
      }
      __syncthreads();
    }
    const u16* hp = hbuf + (size_t)p * (BATCH * HIDDEN);
    float4v acc[4] = {};
    #pragma unroll
    for (int k32 = 0; k32 < 32; k32++) {
      short8v a = cohload16(hp, aoff0 + k32 * 64);
      #pragma unroll
      for (int jj = 0; jj < 4; jj++) {
        int col = jj * 16 + l15;
        int ch = (k32 * 4 + l4) ^ (col & 7);
        short8v b = *(const short8v*)(Wt + col * 1024 + ch * 8);
        acc[jj] = __builtin_amdgcn_mfma_f32_16x16x32_bf16(a, b, acc[jj], 0, 0, 0);
      }
    }
    // epilogue: h = tanh(acc + xp + b_hh); fp32 out (cached) + LDS stage
    #pragma unroll
    for (int jj = 0; jj < 4; jj++)
      #pragma unroll
      for (int q = 0; q < 4; q++) {
        float v = acc[jj][q] + xp[jj][q] + bh[jj];
        float e = __expf(-2.0f * fabsf(v));
        float th = (1.0f - e) / (1.0f + e);
        th = copysignf(th, v);
        outt[(size_t)(rO0 + q) * HIDDEN + cO0 + jj * 16] = th;
        hstage[(lr0 + q) * 64 + jj * 16 + l15] = f2bf(th);
      }
    __syncthreads();  // hstage complete
    // cooperative write-through store of the 8KB h tile (L2-bypass coherent)
    {
      u16* hq = hbuf + (size_t)(p ^ 1) * (BATCH * HIDDEN);
      ushort8v v0 = *(const ushort8v*)(hstage + sr * 64 + sc);
      ushort8v v1 = *(const ushort8v*)(hstage + sr * 64 + sc + 8);
      cohstore16(hq, soff0, v0);
      cohstore16(hq, soff0 + 16, v1);
    }
    asm volatile("s_waitcnt vmcnt(0)" ::: "memory");  // this wave's stores at L3
    __syncthreads();                                  // all waves drained
    if (tid == 0)
      __hip_atomic_store(&flag[g * 16 + jt], (u32)(t + 1), __ATOMIC_RELAXED,
                         __HIP_MEMORY_SCOPE_AGENT);
  }
}

extern "C" void kernel_launch(void* const* d_in, const int* in_sizes, int n_in,
                              void* d_out, int out_size, void* d_ws, size_t ws_size,
                              hipStream_t stream) {
  const int* xseq   = (const int*)d_in[0];
  const float* emb  = (const float*)d_in[1];
  const float* wih  = (const float*)d_in[2];
  const float* bih  = (const float*)d_in[3];
  const float* whh  = (const float*)d_in[4];
  const float* bhh  = (const float*)d_in[5];
  float* out = (float*)d_out;
  char* ws = (char*)d_ws;
  u16* wih16 = (u16*)ws;                      // 1,048,576 B
  u16* hbuf  = (u16*)(ws + 1048576);          // 1,048,576 B (2 x 256 x 1024 bf16)
  u32* flag  = (u32*)(ws + 2097152);          // 256 B (64 value-based flags)

  prep_kernel<<<528, 256, 0, stream>>>(wih, wih16, hbuf, flag);
  gemm_embed<<<16384, 256, 0, stream>>>(xseq, emb, wih16, bih, out);
  (void)hipFuncSetAttribute((const void*)rnn_rec,
                            hipFuncAttributeMaxDynamicSharedMemorySize, 139264);
  rnn_rec<<<64, 256, 139264, stream>>>(whh, bhh, hbuf, out, flag);
}

// Round 7
// 4083.196 us; speedup vs baseline: 3.2140x; 3.2140x over previous
//
#include <hip/hip_runtime.h>
#include <hip/hip_bf16.h>

typedef unsigned short u16;
typedef unsigned int u32;
typedef unsigned long long u64;
typedef __attribute__((ext_vector_type(8))) short short8v;      // MFMA bf16 frag (4 VGPR)
typedef __attribute__((ext_vector_type(8))) unsigned short ushort8v;
typedef __attribute__((ext_vector_type(4))) float float4v;
typedef __attribute__((ext_vector_type(4))) unsigned int uint4v;

#define S_LEN 1024
#define BATCH 256
#define VOCAB 32000
#define EMBED 512
#define HIDDEN 1024
#define BH (BATCH * HIDDEN)

__device__ inline u16 f2bf(float f) {
  return __builtin_bit_cast(u16, __float2bfloat16(f));  // RNE
}

// Coherent (sc0|sc1 = cpol 17: L2-bypass, L3 coherent point) 16B ops.
__device__ inline short8v cohload16(const u16* base, int voff) {
  __amdgpu_buffer_rsrc_t r =
      __builtin_amdgcn_make_buffer_rsrc((void*)base, (short)0, -1, 0x00020000);
  uint4v d = __builtin_amdgcn_raw_buffer_load_b128(r, voff, 0, 17);
  return __builtin_bit_cast(short8v, d);
}
__device__ inline void cohstore16(u16* base, int voff, ushort8v v) {
  __amdgpu_buffer_rsrc_t r =
      __builtin_amdgcn_make_buffer_rsrc((void*)base, (short)0, -1, 0x00020000);
  __builtin_amdgcn_raw_buffer_store_b128(__builtin_bit_cast(uint4v, v), r, voff, 0, 17);
}

// ---------------- prep: W_ih -> bf16, zero hbuf + flags ----------------
__global__ __launch_bounds__(256) void prep_kernel(const float* __restrict__ wih,
                                                   u16* __restrict__ wih16,
                                                   u16* __restrict__ hbuf,
                                                   u32* __restrict__ flag) {
  int i = blockIdx.x * 256 + threadIdx.x;
  const int NW = (HIDDEN * EMBED) / 8;  // 65536
  const int NH = (2 * BH) / 8;          // 65536
  if (i < NW) {
    const float* s = wih + (size_t)i * 8;
    float4v a = *(const float4v*)s;
    float4v b = *(const float4v*)(s + 4);
    ushort8v v;
    v[0]=f2bf(a[0]); v[1]=f2bf(a[1]); v[2]=f2bf(a[2]); v[3]=f2bf(a[3]);
    v[4]=f2bf(b[0]); v[5]=f2bf(b[1]); v[6]=f2bf(b[2]); v[7]=f2bf(b[3]);
    *(ushort8v*)(wih16 + (size_t)i * 8) = v;
  } else if (i < NW + NH) {
    int j = i - NW;
    ushort8v z = {0,0,0,0,0,0,0,0};
    *(ushort8v*)(hbuf + (size_t)j * 8) = z;
  } else if (i < NW + NH + 256) {
    flag[i - NW - NH] = 0u;
  }
}

// ---------------- embed + input projection GEMM ----------------
__global__ __launch_bounds__(256) void gemm_embed(const int* __restrict__ xseq,
                                                  const float* __restrict__ emb,
                                                  const u16* __restrict__ wih16,
                                                  const float* __restrict__ bih,
                                                  float* __restrict__ out) {
  __shared__ u16 At[128 * 64];   // swizzled: chunk ^= (row&7)
  __shared__ u16 Bt[128 * 64];
  __shared__ int idxc[128];
  const int tid = threadIdx.x;
  const int bid = blockIdx.x;
  const int mt = bid >> 3;       // 2048 m-tiles
  const int nt = bid & 7;        // 8 n-tiles
  if (tid < 128) idxc[tid] = xseq[mt * 128 + tid];
  const int lane = tid & 63;
  const int wid = tid >> 6;
  const int wr = wid >> 1, wc = wid & 1;
  float4v acc[4][4] = {};
  __syncthreads();
  for (int kk = 0; kk < EMBED; kk += 64) {
    #pragma unroll
    for (int s = 0; s < 4; s++) {
      int it = tid + s * 256;          // 1024 items = 128 rows x 8 chunks(16B)
      int row = it >> 3, c = it & 7;
      const float* sa = emb + (size_t)idxc[row] * EMBED + kk + c * 8;
      float4v a0 = *(const float4v*)sa;
      float4v a1 = *(const float4v*)(sa + 4);
      ushort8v va;
      va[0]=f2bf(a0[0]); va[1]=f2bf(a0[1]); va[2]=f2bf(a0[2]); va[3]=f2bf(a0[3]);
      va[4]=f2bf(a1[0]); va[5]=f2bf(a1[1]); va[6]=f2bf(a1[2]); va[7]=f2bf(a1[3]);
      *(ushort8v*)(At + row * 64 + ((c ^ (row & 7)) * 8)) = va;
      ushort8v vb = *(const ushort8v*)(wih16 + (size_t)(nt * 128 + row) * EMBED + kk + c * 8);
      *(ushort8v*)(Bt + row * 64 + ((c ^ (row & 7)) * 8)) = vb;
    }
    __syncthreads();
    #pragma unroll
    for (int ks = 0; ks < 2; ks++) {
      short8v af[4], bf[4];
      #pragma unroll
      for (int i = 0; i < 4; i++) {
        int r = wr * 64 + i * 16 + (lane & 15);
        int ca = (ks * 4 + (lane >> 4)) ^ (r & 7);
        af[i] = *(const short8v*)(At + r * 64 + ca * 8);
        int cc = wc * 64 + i * 16 + (lane & 15);
        int cb = (ks * 4 + (lane >> 4)) ^ (cc & 7);
        bf[i] = *(const short8v*)(Bt + cc * 64 + cb * 8);
      }
      #pragma unroll
      for (int i = 0; i < 4; i++)
        #pragma unroll
        for (int j = 0; j < 4; j++)
          acc[i][j] = __builtin_amdgcn_mfma_f32_16x16x32_bf16(af[i], bf[j], acc[i][j], 0, 0, 0);
    }
    __syncthreads();
  }
  #pragma unroll
  for (int j = 0; j < 4; j++) {
    int cg = nt * 128 + wc * 64 + j * 16 + (lane & 15);
    float bias = bih[cg];
    #pragma unroll
    for (int i = 0; i < 4; i++) {
      int rg = mt * 128 + wr * 64 + i * 16 + (lane >> 4) * 4;
      #pragma unroll
      for (int q = 0; q < 4; q++)
        out[(size_t)(rg + q) * HIDDEN + cg] = acc[i][j][q] + bias;
    }
  }
}

// ---------------- recurrence ----------------
// 256 blocks = 16 groups (16 batch rows) x 16 col-tiles (64 hidden cols).
// 4 waves k-split: wave w holds W[64 cols][k-quarter w] permanently in VGPR
// (32 bf16 B-frags = 128 VGPR) -> ZERO W LDS traffic per step. Partial accs
// reduced via small LDS buffer. Exchange = R4/R6-proven protocol: sc0|sc1
// stores (L3 write-through) + vmcnt drain + value flags + relaxed agent poll.
__global__ __launch_bounds__(256) void rnn_rec(const float* __restrict__ whh,
                                               const float* __restrict__ bhh,
                                               u16* __restrict__ hbuf,
                                               float* __restrict__ out,
                                               u32* __restrict__ flag) {
  __shared__ float red[4][16][65];   // [wave][row][col] fp32, padded (+1)
  __shared__ u16 hstage[16 * 64];    // h tile staging for coop store
  const int tid = threadIdx.x;
  const int lane = tid & 63, w = tid >> 6;   // wave w owns k in [w*256, w*256+256)
  const int l15 = lane & 15, l4 = lane >> 4;
  const int g = blockIdx.x & 15;             // batch rows [g*16, g*16+16)
  const int jt = blockIdx.x >> 4;            // hidden cols [jt*64, jt*64+64)

  // prologue: W_hh B-frags into registers (fully static indexing)
  short8v Wf[4][8];
  #pragma unroll
  for (int jj = 0; jj < 4; jj++)
    #pragma unroll
    for (int kq = 0; kq < 8; kq++) {
      const float* s = whh + (size_t)(jt * 64 + jj * 16 + l15) * HIDDEN
                       + w * 256 + kq * 32 + l4 * 8;
      float4v a = *(const float4v*)s;
      float4v b = *(const float4v*)(s + 4);
      ushort8v v;
      v[0]=f2bf(a[0]); v[1]=f2bf(a[1]); v[2]=f2bf(a[2]); v[3]=f2bf(a[3]);
      v[4]=f2bf(b[0]); v[5]=f2bf(b[1]); v[6]=f2bf(b[2]); v[7]=f2bf(b[3]);
      Wf[jj][kq] = __builtin_bit_cast(short8v, v);
    }
  const int rr0 = (tid >> 6) * 4;        // reduction rows (this thread: rr0..rr0+3)
  const int cc  = tid & 63;              // reduction col
  const float bhc = bhh[jt * 64 + cc];
  const int aoff = ((g * 16 + l15) * HIDDEN + w * 256 + l4 * 8) * 2;  // h-frag byte off

  for (int t = 0; t < S_LEN; t++) {
    const int p = t & 1;
    float* outt = out + (size_t)t * BH;
    // xp prefetch (in flight during the poll)
    float xp[4];
    #pragma unroll
    for (int j = 0; j < 4; j++)
      xp[j] = outt[(size_t)(g * 16 + rr0 + j) * HIDDEN + jt * 64 + cc];
    // wait for the 16 producers of h_{t-1} in this group (parallel poll)
    if (t > 0) {
      if (tid < 16) {
        u32* f = flag + g * 16 + tid;
        while (__hip_atomic_load(f, __ATOMIC_RELAXED, __HIP_MEMORY_SCOPE_AGENT) < (u32)t) { }
      }
      __syncthreads();
    }
    // h loads (8 x 16B, coherent, compiler-pipelined) + MFMA from registers
    const u16* hp = hbuf + (size_t)p * BH;
    short8v a[8];
    #pragma unroll
    for (int kq = 0; kq < 8; kq++)
      a[kq] = cohload16(hp, aoff + kq * 64);
    float4v accp[4] = {};
    #pragma unroll
    for (int kq = 0; kq < 8; kq++)
      #pragma unroll
      for (int jj = 0; jj < 4; jj++)
        accp[jj] = __builtin_amdgcn_mfma_f32_16x16x32_bf16(a[kq], Wf[jj][kq], accp[jj], 0, 0, 0);
    // partials -> LDS
    #pragma unroll
    for (int jj = 0; jj < 4; jj++)
      #pragma unroll
      for (int q = 0; q < 4; q++)
        red[w][l4 * 4 + q][jj * 16 + l15] = accp[jj][q];
    __syncthreads();
    // reduce + epilogue: h = tanh(sum + xp + b_hh)
    #pragma unroll
    for (int j = 0; j < 4; j++) {
      int r = rr0 + j;
      float s = red[0][r][cc] + red[1][r][cc] + red[2][r][cc] + red[3][r][cc];
      float v = s + xp[j] + bhc;
      float e = __expf(-2.0f * fabsf(v));
      float th = (1.0f - e) / (1.0f + e);
      th = copysignf(th, v);
      outt[(size_t)(g * 16 + r) * HIDDEN + jt * 64 + cc] = th;
      hstage[r * 64 + cc] = f2bf(th);
    }
    __syncthreads();  // hstage complete (also fences red reuse)
    // cooperative write-through store of the 2KB h tile
    if (tid < 128) {
      u16* hq = hbuf + (size_t)(p ^ 1) * BH;
      ushort8v v = *(const ushort8v*)(hstage + (tid >> 3) * 64 + (tid & 7) * 8);
      cohstore16(hq, ((g * 16 + (tid >> 3)) * HIDDEN + jt * 64 + (tid & 7) * 8) * 2, v);
    }
    asm volatile("s_waitcnt vmcnt(0)" ::: "memory");  // stores at coherent point
    __syncthreads();                                  // all waves drained
    if (tid == 0)
      __hip_atomic_store(&flag[g * 16 + jt], (u32)(t + 1), __ATOMIC_RELAXED,
                         __HIP_MEMORY_SCOPE_AGENT);
  }
}

extern "C" void kernel_launch(void* const* d_in, const int* in_sizes, int n_in,
                              void* d_out, int out_size, void* d_ws, size_t ws_size,
                              hipStream_t stream) {
  const int* xseq   = (const int*)d_in[0];
  const float* emb  = (const float*)d_in[1];
  const float* wih  = (const float*)d_in[2];
  const float* bih  = (const float*)d_in[3];
  const float* whh  = (const float*)d_in[4];
  const float* bhh  = (const float*)d_in[5];
  float* out = (float*)d_out;
  char* ws = (char*)d_ws;
  u16* wih16 = (u16*)ws;                      // 1,048,576 B
  u16* hbuf  = (u16*)(ws + 1048576);          // 1,048,576 B (2 x 256 x 1024 bf16)
  u32* flag  = (u32*)(ws + 2097152);          // 1,024 B (256 value-based flags)

  prep_kernel<<<513, 256, 0, stream>>>(wih, wih16, hbuf, flag);
  gemm_embed<<<16384, 256, 0, stream>>>(xseq, emb, wih16, bih, out);
  rnn_rec<<<256, 256, 0, stream>>>(whh, bhh, hbuf, out, flag);
}